// Round 2
// 97.000 us; speedup vs baseline: 1.2517x; 1.2517x over previous
//
#include <hip/hip_runtime.h>

// Sinkhorn top-k, sorted-value domain, x <- 1/(Mx), 200 apps.
// R18 = R17 resubmitted (previous bench died to container infra failure, no
// signal). 4 waves x 2 rows/lane (256 threads): serial per-app stream per
// wave drops ~4x vs R16 (88 dots -> 22). Window exchange via double-buffered,
// zero-padded LDS: store 1 dword, 1 barrier, read 11 consecutive dwords
// (conflict-free; 2-lane/bank aliasing is free on gfx950). Zero pads
// reproduce R16's DPP 0-fill edge semantics exactly; banding, window mapping
// (row pairs share an 11-dword span, radius 10), and the 200-app schedule are
// unchanged, so absmax should stay ~7.8e-3.

#define N      512
#define BATCH  16
#define KTOP   50
#define NAPPS  200
#define NJ     11          // window dwords per row pair
#define COEF   1442.6950408889634f   // log2(e)/EPSILON, EPSILON=1e-3
#define ONEH2  0x3C003C00u
#define NT     256         // threads per block = 4 waves
#define XPAD   5           // zero pad dwords at each end of x buffer
#define XLEN   (NT + 2 * XPAD)

typedef _Float16 h2 __attribute__((ext_vector_type(2)));

static __device__ __forceinline__ h2 pack2(float a, float b) {
    return __builtin_bit_cast(h2, __builtin_amdgcn_cvt_pkrtz(a, b));
}
static __device__ __forceinline__ h2 uh(unsigned v) {
    return __builtin_bit_cast(h2, v);
}

__global__
__attribute__((amdgpu_flat_work_group_size(NT, NT)))
void sinkhorn_topk_kernel(const float* __restrict__ scores,
                          float* __restrict__ out) {
    __shared__ __align__(16) float tv[N];
    __shared__ int                 ti[N];
    __shared__ unsigned            xb[2][XLEN];   // double-buffered x dwords

    const int g = threadIdx.x;              // 0..255, owns rows 2g, 2g+1
    const int b = blockIdx.x;

    ((float2*)tv)[g] = ((const float2*)(scores + b * N))[g];
    ti[2 * g]     = 2 * g;
    ti[2 * g + 1] = 2 * g + 1;
    if (g < XPAD) {                         // zero pads (DPP 0-fill semantics)
        xb[0][g] = 0u;            xb[1][g] = 0u;
        xb[0][XLEN - 1 - g] = 0u; xb[1][XLEN - 1 - g] = 0u;
    }
    xb[0][XPAD + g] = ONEH2;                // x_0 = 1.0 pairs
    __syncthreads();

    // ---- bitonic sort, descending (256 pairs, 1 per thread) ----
    for (int k = 2; k <= N; k <<= 1) {
        for (int j = k >> 1; j > 0; j >>= 1) {
            int i = ((g & ~(j - 1)) << 1) | (g & (j - 1));
            int p = i | j;
            float va = tv[i], vb = tv[p];
            bool up = ((i & k) == 0);
            bool sw = up ? (va < vb) : (va > vb);
            if (sw) {
                tv[i] = vb; tv[p] = va;
                int t_ = ti[i]; ti[i] = ti[p]; ti[p] = t_;
            }
            __syncthreads();
        }
    }

    // ---- K band: both rows of the pair use window dwords 0..10 ----
    const int gb = 2 * g - 10;              // global half-index of window dword 0
    const float t0 = tv[2 * g], t1 = tv[2 * g + 1];
    h2 K2[2][NJ];                           // 22 dwords/lane
#pragma unroll
    for (int d = 0; d < NJ; ++d) {
        int g0 = gb + 2 * d, g1 = g0 + 1;
        int c0 = min(max(g0, 0), N - 1), c1 = min(max(g1, 0), N - 1);
        float s0 = tv[c0], s1 = tv[c1];
        float d00 = t0 - s0, d01 = t0 - s1;
        float d10 = t1 - s0, d11 = t1 - s1;
        K2[0][d] = pack2(exp2f(-COEF * d00 * d00), exp2f(-COEF * d01 * d01));
        K2[1][d] = pack2(exp2f(-COEF * d10 * d10), exp2f(-COEF * d11 * d11));
    }

    // ---- 200 apps: read window from rb, dot, rcp, store to wb, barrier ----
    unsigned w[NJ];
    unsigned x = ONEH2;

    auto run_app = [&](const unsigned* rb, unsigned* wb) {
#pragma unroll
        for (int d = 0; d < NJ; ++d) w[d] = rb[g + d];   // dwords g-5..g+5
        // 4 chains (even/odd split per row) for dep-latency cover
        float a0 = __builtin_amdgcn_fdot2(K2[0][0], uh(w[0]), 0.f, false);
        float a1 = __builtin_amdgcn_fdot2(K2[1][0], uh(w[0]), 0.f, false);
        float b0 = __builtin_amdgcn_fdot2(K2[0][1], uh(w[1]), 0.f, false);
        float b1 = __builtin_amdgcn_fdot2(K2[1][1], uh(w[1]), 0.f, false);
#pragma unroll
        for (int d = 2; d < NJ; d += 2) {
            a0 = __builtin_amdgcn_fdot2(K2[0][d], uh(w[d]), a0, false);
            a1 = __builtin_amdgcn_fdot2(K2[1][d], uh(w[d]), a1, false);
            if (d + 1 < NJ) {
                b0 = __builtin_amdgcn_fdot2(K2[0][d + 1], uh(w[d + 1]), b0, false);
                b1 = __builtin_amdgcn_fdot2(K2[1][d + 1], uh(w[d + 1]), b1, false);
            }
        }
        float s0 = a0 + b0, s1 = a1 + b1;
        x = __builtin_bit_cast(unsigned,
                pack2(__builtin_amdgcn_rcpf(s0), __builtin_amdgcn_rcpf(s1)));
        if (wb) {
            wb[XPAD + g] = x;
            __syncthreads();
        }
    };

    unsigned* B0 = &xb[0][0];
    unsigned* B1 = &xb[1][0];
#pragma unroll 1
    for (int it = 0; it < (NAPPS - 2) / 2; ++it) {   // apps 0..197
        run_app(B0, B1);
        run_app(B1, B0);
    }
    run_app(B0, B1);            // app 198
    run_app(B1, nullptr);       // app 199: x final; w = window of app-199 state

    // ---- epilogue: out_row = r_a * sum_{gc<K} K[a][gc] c_gc ----
    unsigned cmask[NJ];
#pragma unroll
    for (int d = 0; d < NJ; ++d) {
        int g0 = gb + 2 * d, g1 = g0 + 1;
        h2 cw = uh(w[d]);
        float c0 = (g0 >= 0 && g0 < KTOP) ? (float)cw[0] : 0.f;
        float c1 = (g1 >= 0 && g1 < KTOP) ? (float)cw[1] : 0.f;
        cmask[d] = __builtin_bit_cast(unsigned, pack2(c0, c1));
    }
    float k0 = 0.f, k1 = 0.f;
#pragma unroll
    for (int d = 0; d < NJ; ++d) {
        k0 = __builtin_amdgcn_fdot2(K2[0][d], uh(cmask[d]), k0, false);
        k1 = __builtin_amdgcn_fdot2(K2[1][d], uh(cmask[d]), k1, false);
    }
    h2 xr = uh(x);
    out[b * N + ti[2 * g]]     = (float)xr[0] * k0;
    out[b * N + ti[2 * g + 1]] = (float)xr[1] * k1;
}

extern "C" void kernel_launch(void* const* d_in, const int* in_sizes, int n_in,
                              void* d_out, int out_size, void* d_ws, size_t ws_size,
                              hipStream_t stream) {
    const float* scores = (const float*)d_in[0];
    float* out = (float*)d_out;
    sinkhorn_topk_kernel<<<dim3(BATCH), dim3(NT), 0, stream>>>(scores, out);
}